// Round 1
// baseline (1420.309 us; speedup 1.0000x reference)
//
#include <hip/hip_runtime.h>
#include <hip/hip_bf16.h>

// Problem constants (from reference file):
//   embeddings: (10240, 32000) fp32,  targets: (2048,) int32
//   out = -(1/2048) * sum_i  emb[i, t_i] / (emb[i+2048,t_i] + emb[i+4096,t_i]
//                                          + emb[i+6144,t_i] + emb[i+8192,t_i])
// Only 5 scalars per row are live -> 10,240 gathered loads total.

#define DIM 2048
#define NCLASSES 32000LL
#define BLOCK 1024

__global__ __launch_bounds__(BLOCK)
void MMI_softmax_Loss_70566312673356_kernel(const float* __restrict__ emb,
                                            const int* __restrict__ targets,
                                            float* __restrict__ out) {
    const int tid = threadIdx.x;

    float acc = 0.0f;
    // 2048 rows / 1024 threads = 2 rows per thread; all 10 loads independent.
    #pragma unroll
    for (int r = 0; r < DIM / BLOCK; ++r) {
        const int i = tid + r * BLOCK;
        const int c = targets[i];
        const float* col = emb + (long long)c;
        const float ex = col[(long long)i * NCLASSES];
        const float s1 = col[(long long)(i + 2048) * NCLASSES];
        const float s2 = col[(long long)(i + 4096) * NCLASSES];
        const float s3 = col[(long long)(i + 6144) * NCLASSES];
        const float s4 = col[(long long)(i + 8192) * NCLASSES];
        acc += ex / (s1 + s2 + s3 + s4);
    }

    // Wave-64 shuffle reduction.
    #pragma unroll
    for (int off = 32; off > 0; off >>= 1)
        acc += __shfl_down(acc, off, 64);

    __shared__ float wave_sums[BLOCK / 64];   // 16 partials
    const int wave = tid >> 6;
    const int lane = tid & 63;
    if (lane == 0) wave_sums[wave] = acc;
    __syncthreads();

    // Final reduce in wave 0 (all 64 lanes active -> shuffles well-defined).
    if (wave == 0) {
        float v = (lane < BLOCK / 64) ? wave_sums[lane] : 0.0f;
        #pragma unroll
        for (int off = 8; off > 0; off >>= 1)
            v += __shfl_down(v, off, 64);
        if (lane == 0)
            out[0] = -v * (1.0f / (float)DIM);
    }
}

extern "C" void kernel_launch(void* const* d_in, const int* in_sizes, int n_in,
                              void* d_out, int out_size, void* d_ws, size_t ws_size,
                              hipStream_t stream) {
    const float* emb     = (const float*)d_in[0];
    const int*   targets = (const int*)d_in[1];
    float*       out     = (float*)d_out;

    MMI_softmax_Loss_70566312673356_kernel<<<1, BLOCK, 0, stream>>>(emb, targets, out);
}